// Round 3
// baseline (1439.185 us; speedup 1.0000x reference)
//
#include <hip/hip_runtime.h>
#include <math.h>

#define SEQ 12
#define NBATCH 16384   // BC*NODES
#define FEAT 32
#define HID 64

// packed-weight layout offsets (floats) inside d_ws
#define WP_IH0 0
#define WP_HH0 6144
#define WP_IH1 18432
#define WP_HH1 30720
#define WP_TOTAL 43008
#define Z_OFF WP_TOTAL

__device__ __forceinline__ float sigf(float x) { return 1.0f / (1.0f + __expf(-x)); }
__device__ __forceinline__ float tanh_fast(float x) { return 2.0f / (1.0f + __expf(-2.0f * x)) - 1.0f; }

#define DOT4(acc, A_, B_)                                   \
  acc = fmaf((A_).x, (B_).x, acc);                          \
  acc = fmaf((A_).y, (B_).y, acc);                          \
  acc = fmaf((A_).z, (B_).z, acc);                          \
  acc = fmaf((A_).w, (B_).w, acc);

// ---------------------------------------------------------------------------
// Pack weights transposed + k4-interleaved:
//   wp[((k>>2)*3 + g)*256 + j*4 + (k&3)] = W[(g*64+j)*K + k]
// lane j reads float4 = W[g*64+j][4k..4k+3]; lanes j=0..63 are 16B-strided
// -> perfectly coalesced 1KB fetches, identical addresses across all waves
// -> L1/L2 resident (168KB total).
// ---------------------------------------------------------------------------
__global__ void prep_kernel(const float* __restrict__ w_ih0, const float* __restrict__ w_hh0,
                            const float* __restrict__ w_ih1, const float* __restrict__ w_hh1,
                            float* __restrict__ wp)
{
  for (int i = blockIdx.x * blockDim.x + threadIdx.x; i < WP_TOTAL; i += gridDim.x * blockDim.x) {
    const float* src;
    int K, rel;
    if (i < WP_HH0)      { src = w_ih0; K = 32; rel = i; }
    else if (i < WP_IH1) { src = w_hh0; K = 64; rel = i - WP_HH0; }
    else if (i < WP_HH1) { src = w_ih1; K = 64; rel = i - WP_IH1; }
    else                 { src = w_hh1; K = 64; rel = i - WP_HH1; }
    int kr = rel & 3;
    int jj = (rel >> 2) & 63;
    int rest = rel >> 8;       // = k4*3 + g
    int g = rest % 3;
    int k4 = rest / 3;
    wp[i] = src[(g * 64 + jj) * K + k4 * 4 + kr];
  }
}

// ---------------------------------------------------------------------------
// Fused 2-layer GRU. Block = 256 (4 waves). Each WAVE owns 8 samples (SS=8);
// lane j owns hidden unit j. Weights stream from global (L1/L2-hot packed
// layout); only h-state lives in LDS, and it is WAVE-PRIVATE -> zero
// __syncthreads in the recurrence. 16KB LDS -> no LDS occupancy limit.
// ---------------------------------------------------------------------------
__global__ __launch_bounds__(256, 2) void gru_kernel(
    const float* __restrict__ x,      // [12][16384][32]
    const float* __restrict__ wpack,  // packed weights
    const float* __restrict__ b_ih0, const float* __restrict__ b_hh0,
    const float* __restrict__ b_ih1, const float* __restrict__ b_hh1,
    float* __restrict__ zout)         // [2][16384][64]
{
  __shared__ float h0s[32][64];
  __shared__ float h1s[32][64];
  const int tid = threadIdx.x;
  const int j  = tid & 63;
  const int sg = tid >> 6;           // wave id 0..3
  const int wbase = sg * 8;          // this wave's local sample base
  const int s0 = blockIdx.x * 32;    // block's global sample base

  const float br0  = b_ih0[j]      + b_hh0[j];
  const float bz0  = b_ih0[64 + j] + b_hh0[64 + j];
  const float bni0 = b_ih0[128 + j];
  const float bnh0 = b_hh0[128 + j];
  const float br1  = b_ih1[j]      + b_hh1[j];
  const float bz1  = b_ih1[64 + j] + b_hh1[64 + j];
  const float bni1 = b_ih1[128 + j];
  const float bnh1 = b_hh1[128 + j];

  float h0r[8], h1r[8];
  #pragma unroll
  for (int ss = 0; ss < 8; ss++) {
    h0r[ss] = 0.f; h1r[ss] = 0.f;
    h0s[wbase + ss][j] = 0.f;
    h1s[wbase + ss][j] = 0.f;
  }

  const float4* wih0g = (const float4*)(wpack + WP_IH0);
  const float4* whh0g = (const float4*)(wpack + WP_HH0);
  const float4* wih1g = (const float4*)(wpack + WP_IH1);
  const float4* whh1g = (const float4*)(wpack + WP_HH1);

  for (int t = 0; t < SEQ; t++) {
    float ar[8], az[8], ani[8], anh[8];
    #pragma unroll
    for (int ss = 0; ss < 8; ss++) { ar[ss] = br0; az[ss] = bz0; ani[ss] = bni0; anh[ss] = bnh0; }

    // ---- layer 0: gi = x @ W_ih0^T (K=32) ----
    #pragma unroll
    for (int k4 = 0; k4 < 8; k4++) {
      float4 wr = wih0g[(k4 * 3 + 0) * 64 + j];
      float4 wz = wih0g[(k4 * 3 + 1) * 64 + j];
      float4 wn = wih0g[(k4 * 3 + 2) * 64 + j];
      #pragma unroll
      for (int ss = 0; ss < 8; ss++) {
        // wave-uniform address -> single broadcast fetch, L1-hot
        float4 xv = *(const float4*)(x + ((size_t)t * NBATCH + (s0 + wbase + ss)) * FEAT + k4 * 4);
        DOT4(ar[ss],  wr, xv);
        DOT4(az[ss],  wz, xv);
        DOT4(ani[ss], wn, xv);
      }
    }
    // ---- layer 0: gh = h0 @ W_hh0^T (K=64) ----
    #pragma unroll
    for (int k4 = 0; k4 < 16; k4++) {
      float4 wr = whh0g[(k4 * 3 + 0) * 64 + j];
      float4 wz = whh0g[(k4 * 3 + 1) * 64 + j];
      float4 wn = whh0g[(k4 * 3 + 2) * 64 + j];
      #pragma unroll
      for (int ss = 0; ss < 8; ss++) {
        float4 hv = *(const float4*)&h0s[wbase + ss][k4 * 4];   // broadcast
        DOT4(ar[ss],  wr, hv);
        DOT4(az[ss],  wz, hv);
        DOT4(anh[ss], wn, hv);
      }
    }
    float h0n[8];
    #pragma unroll
    for (int ss = 0; ss < 8; ss++) {
      float rg = sigf(ar[ss]);
      float zg = sigf(az[ss]);
      float ng = tanh_fast(fmaf(rg, anh[ss], ani[ss]));
      h0n[ss] = fmaf(zg, h0r[ss] - ng, ng);   // (1-z)*n + z*h
    }
    // wave-private LDS: in-wave ds ordering (lgkmcnt) is sufficient, no barrier
    #pragma unroll
    for (int ss = 0; ss < 8; ss++) { h0s[wbase + ss][j] = h0n[ss]; h0r[ss] = h0n[ss]; }

    // ---- layer 1 ----
    #pragma unroll
    for (int ss = 0; ss < 8; ss++) { ar[ss] = br1; az[ss] = bz1; ani[ss] = bni1; anh[ss] = bnh1; }
    #pragma unroll
    for (int k4 = 0; k4 < 16; k4++) {
      float4 wr = wih1g[(k4 * 3 + 0) * 64 + j];
      float4 wz = wih1g[(k4 * 3 + 1) * 64 + j];
      float4 wn = wih1g[(k4 * 3 + 2) * 64 + j];
      #pragma unroll
      for (int ss = 0; ss < 8; ss++) {
        float4 hv = *(const float4*)&h0s[wbase + ss][k4 * 4];   // new h0, same wave
        DOT4(ar[ss],  wr, hv);
        DOT4(az[ss],  wz, hv);
        DOT4(ani[ss], wn, hv);
      }
    }
    #pragma unroll
    for (int k4 = 0; k4 < 16; k4++) {
      float4 wr = whh1g[(k4 * 3 + 0) * 64 + j];
      float4 wz = whh1g[(k4 * 3 + 1) * 64 + j];
      float4 wn = whh1g[(k4 * 3 + 2) * 64 + j];
      #pragma unroll
      for (int ss = 0; ss < 8; ss++) {
        float4 hv = *(const float4*)&h1s[wbase + ss][k4 * 4];
        DOT4(ar[ss],  wr, hv);
        DOT4(az[ss],  wz, hv);
        DOT4(anh[ss], wn, hv);
      }
    }
    float h1n[8];
    #pragma unroll
    for (int ss = 0; ss < 8; ss++) {
      float rg = sigf(ar[ss]);
      float zg = sigf(az[ss]);
      float ng = tanh_fast(fmaf(rg, anh[ss], ani[ss]));
      h1n[ss] = fmaf(zg, h1r[ss] - ng, ng);
    }
    #pragma unroll
    for (int ss = 0; ss < 8; ss++) { h1s[wbase + ss][j] = h1n[ss]; h1r[ss] = h1n[ss]; }
  }

  #pragma unroll
  for (int ss = 0; ss < 8; ss++) {
    int s = s0 + wbase + ss;
    zout[(size_t)s * 64 + j]            = h0r[ss];
    zout[(size_t)(NBATCH + s) * 64 + j] = h1r[ss];
  }
}

// ---------------------------------------------------------------------------
// GAT: flash-style fused attention per (layer*bc, 64-row tile).
// Block = 256 threads as 16x16 (r,c); 4x4 micro-tile with CONFLICT-FREE
// mapping: S-rows = r+16*ri, S-cols = c+16*ci (K-row reads hit banks 4c%32
// -> 2-way = free), O-cols = c*4+ci (V reads stay contiguous b128).
// ---------------------------------------------------------------------------
__global__ __launch_bounds__(256, 3) void gat_kernel(const float* __restrict__ z,
                                                     const int* __restrict__ mask,
                                                     float* __restrict__ out)
{
  __shared__ float Q [64][68];
  __shared__ float Kt[64][68];
  __shared__ float P [64][68];
  const int tid = threadIdx.x;
  const int rt = blockIdx.x & 15;    // row tile
  const int lb = blockIdx.x >> 4;    // l*16 + b  (0..31)
  const float* zb = z + (size_t)lb * 1024 * 64;
  const int n0 = rt * 64;

  // stage Q
  for (int i = tid; i < 1024; i += 256) {
    int row = i >> 4, c4 = i & 15;
    *(float4*)&Q[row][c4 * 4] = ((const float4*)(zb + (size_t)(n0 + row) * 64))[c4];
  }

  const int r = tid >> 4, c = tid & 15;   // r: 0..15, c: 0..15
  float O[4][4];
  float Mr[4], Dr[4];
  #pragma unroll
  for (int a = 0; a < 4; a++) {
    Mr[a] = -INFINITY; Dr[a] = 0.f;
    #pragma unroll
    for (int b2 = 0; b2 < 4; b2++) O[a][b2] = 0.f;
  }

  for (int mt = 0; mt < 16; mt++) {
    __syncthreads();   // prev PV reads of Kt done (also covers initial Q staging)
    for (int i = tid; i < 1024; i += 256) {
      int row = i >> 4, c4 = i & 15;
      *(float4*)&Kt[row][c4 * 4] = ((const float4*)(zb + (size_t)(mt * 64 + row) * 64))[c4];
    }
    __syncthreads();

    // S[ri][ci] = Q[r+16ri] . Kt[c+16ci]
    float S[4][4];
    #pragma unroll
    for (int a = 0; a < 4; a++)
      #pragma unroll
      for (int b2 = 0; b2 < 4; b2++) S[a][b2] = 0.f;
    #pragma unroll
    for (int k4 = 0; k4 < 16; k4++) {
      float4 q0 = *(const float4*)&Q[r + 16 * 0][k4 * 4];
      float4 q1 = *(const float4*)&Q[r + 16 * 1][k4 * 4];
      float4 q2 = *(const float4*)&Q[r + 16 * 2][k4 * 4];
      float4 q3 = *(const float4*)&Q[r + 16 * 3][k4 * 4];
      float4 k0 = *(const float4*)&Kt[c + 16 * 0][k4 * 4];
      float4 k1 = *(const float4*)&Kt[c + 16 * 1][k4 * 4];
      float4 k2 = *(const float4*)&Kt[c + 16 * 2][k4 * 4];
      float4 k3 = *(const float4*)&Kt[c + 16 * 3][k4 * 4];
      DOT4(S[0][0], q0, k0); DOT4(S[0][1], q0, k1); DOT4(S[0][2], q0, k2); DOT4(S[0][3], q0, k3);
      DOT4(S[1][0], q1, k0); DOT4(S[1][1], q1, k1); DOT4(S[1][2], q1, k2); DOT4(S[1][3], q1, k3);
      DOT4(S[2][0], q2, k0); DOT4(S[2][1], q2, k1); DOT4(S[2][2], q2, k2); DOT4(S[2][3], q2, k3);
      DOT4(S[3][0], q3, k0); DOT4(S[3][1], q3, k1); DOT4(S[3][2], q3, k2); DOT4(S[3][3], q3, k3);
    }

    // leaky_relu * mask, masked_fill(==0, -1e16)
    #pragma unroll
    for (int ri = 0; ri < 4; ri++) {
      #pragma unroll
      for (int ci = 0; ci < 4; ci++) {
        int mm = mask[(size_t)(n0 + r + 16 * ri) * 1024 + mt * 64 + c + 16 * ci];
        float v = S[ri][ci];
        float lr = v > 0.f ? v : 0.1f * v;
        float a = mm ? lr : 0.f;
        S[ri][ci] = (a == 0.f) ? -1e16f : a;
      }
    }

    // online softmax update (row r+16ri shared by the 16 c-lanes)
    #pragma unroll
    for (int ri = 0; ri < 4; ri++) {
      float m = fmaxf(fmaxf(S[ri][0], S[ri][1]), fmaxf(S[ri][2], S[ri][3]));
      #pragma unroll
      for (int w = 1; w < 16; w <<= 1) m = fmaxf(m, __shfl_xor(m, w, 16));
      float newM = fmaxf(Mr[ri], m);
      float sc = __expf(Mr[ri] - newM);   // first tile: exp(-inf)=0
      float ps = 0.f;
      #pragma unroll
      for (int ci = 0; ci < 4; ci++) {
        float p = __expf(S[ri][ci] - newM);
        S[ri][ci] = p;
        ps += p;
      }
      #pragma unroll
      for (int w = 1; w < 16; w <<= 1) ps += __shfl_xor(ps, w, 16);
      Dr[ri] = Dr[ri] * sc + ps;
      Mr[ri] = newM;
      #pragma unroll
      for (int ci = 0; ci < 4; ci++) O[ri][ci] *= sc;
      // P rows r+16ri are produced and consumed by the SAME wave -> no barrier
      #pragma unroll
      for (int ci = 0; ci < 4; ci++) P[r + 16 * ri][c + 16 * ci] = S[ri][ci];
    }

    // O[ri][ci] += sum_m P[r+16ri][m] * V[m][c*4+ci]   (V = Kt rows)
    #pragma unroll
    for (int m4 = 0; m4 < 16; m4++) {
      float4 v0 = *(const float4*)&Kt[m4 * 4 + 0][c * 4];
      float4 v1 = *(const float4*)&Kt[m4 * 4 + 1][c * 4];
      float4 v2 = *(const float4*)&Kt[m4 * 4 + 2][c * 4];
      float4 v3 = *(const float4*)&Kt[m4 * 4 + 3][c * 4];
      #pragma unroll
      for (int ri = 0; ri < 4; ri++) {
        float4 p4 = *(const float4*)&P[r + 16 * ri][m4 * 4];
        O[ri][0] = fmaf(p4.x, v0.x, O[ri][0]); O[ri][1] = fmaf(p4.x, v0.y, O[ri][1]);
        O[ri][2] = fmaf(p4.x, v0.z, O[ri][2]); O[ri][3] = fmaf(p4.x, v0.w, O[ri][3]);
        O[ri][0] = fmaf(p4.y, v1.x, O[ri][0]); O[ri][1] = fmaf(p4.y, v1.y, O[ri][1]);
        O[ri][2] = fmaf(p4.y, v1.z, O[ri][2]); O[ri][3] = fmaf(p4.y, v1.w, O[ri][3]);
        O[ri][0] = fmaf(p4.z, v2.x, O[ri][0]); O[ri][1] = fmaf(p4.z, v2.y, O[ri][1]);
        O[ri][2] = fmaf(p4.z, v2.z, O[ri][2]); O[ri][3] = fmaf(p4.z, v2.w, O[ri][3]);
        O[ri][0] = fmaf(p4.w, v3.x, O[ri][0]); O[ri][1] = fmaf(p4.w, v3.y, O[ri][1]);
        O[ri][2] = fmaf(p4.w, v3.z, O[ri][2]); O[ri][3] = fmaf(p4.w, v3.w, O[ri][3]);
      }
    }
  }

  // epilogue: divide by denom, store (rows r+16ri, cols c*4..c*4+3)
  #pragma unroll
  for (int ri = 0; ri < 4; ri++) {
    float inv = 1.0f / Dr[ri];
    float4 o4 = make_float4(O[ri][0] * inv, O[ri][1] * inv, O[ri][2] * inv, O[ri][3] * inv);
    *(float4*)(out + ((size_t)lb * 1024 + n0 + r + 16 * ri) * 64 + c * 4) = o4;
  }
}

extern "C" void kernel_launch(void* const* d_in, const int* in_sizes, int n_in,
                              void* d_out, int out_size, void* d_ws, size_t ws_size,
                              hipStream_t stream) {
  const float* h     = (const float*)d_in[0];
  const int*   mask  = (const int*)d_in[1];
  const float* w_ih0 = (const float*)d_in[2];
  const float* w_hh0 = (const float*)d_in[3];
  const float* b_ih0 = (const float*)d_in[4];
  const float* b_hh0 = (const float*)d_in[5];
  const float* w_ih1 = (const float*)d_in[6];
  const float* w_hh1 = (const float*)d_in[7];
  const float* b_ih1 = (const float*)d_in[8];
  const float* b_hh1 = (const float*)d_in[9];
  float* out = (float*)d_out;
  float* ws  = (float*)d_ws;
  float* wpack = ws;
  float* zws   = ws + Z_OFF;

  prep_kernel<<<24, 256, 0, stream>>>(w_ih0, w_hh0, w_ih1, w_hh1, wpack);
  gru_kernel<<<512, 256, 0, stream>>>(h, wpack, b_ih0, b_hh0, b_ih1, b_hh1, zws);
  gat_kernel<<<512, 256, 0, stream>>>(zws, mask, out);
}

// Round 4
// 305.188 us; speedup vs baseline: 4.7157x; 4.7157x over previous
//
#include <hip/hip_runtime.h>
#include <math.h>

#define SEQ 12
#define NBATCH 16384   // BC*NODES
#define FEAT 32
#define HID 64

// ---- fallback packed-weight layout (floats, round-2 format) ----
#define WP_IH0 0
#define WP_HH0 6144
#define WP_IH1 18432
#define WP_HH1 30720
#define WP_TOTAL 43008

typedef __attribute__((ext_vector_type(8))) short bf16x8;   // 8 bf16 = 4 VGPR
typedef __attribute__((ext_vector_type(4))) float f32x4;

#define MFMA_B16(A,B,C) __builtin_amdgcn_mfma_f32_16x16x32_bf16((A),(B),(C),0,0,0)

union B8u { unsigned short s[8]; bf16x8 v; };

__device__ __forceinline__ float sigf(float x) { return 1.0f / (1.0f + __expf(-x)); }
__device__ __forceinline__ float tanh_fast(float x) { return 2.0f / (1.0f + __expf(-2.0f * x)) - 1.0f; }

#define DOT4(acc, A_, B_)                                   \
  acc = fmaf((A_).x, (B_).x, acc);                          \
  acc = fmaf((A_).y, (B_).y, acc);                          \
  acc = fmaf((A_).z, (B_).z, acc);                          \
  acc = fmaf((A_).w, (B_).w, acc);

// ===========================================================================
// FAST PATH: MFMA GRU.
// Weights pre-packed as B-fragments for mfma_f32_16x16x32_bf16:
//   B-frag layout: lane l holds W[g = ct*16 + (l&15)][k = ks*32 + (l>>4)*8 + e]
//   storage: [matrix][ct*nks+ks][plane(hi,lo)][lane][e]  (1KB per frag)
// hi = fp32 truncated to bf16, lo = bf16(x - hi)  (3-term products ~fp32 acc.)
// ===========================================================================
__global__ void prep_frag_kernel(const float* __restrict__ w_ih0, const float* __restrict__ w_hh0,
                                 const float* __restrict__ w_ih1, const float* __restrict__ w_hh1,
                                 unsigned short* __restrict__ wf)
{
  int i = blockIdx.x * blockDim.x + threadIdx.x;   // 0..43007
  if (i >= 43008) return;
  const float* src; int K, rel, baseS;
  if (i < 6144)       { src = w_ih0; K = 32; rel = i;         baseS = 0; }
  else if (i < 18432) { src = w_hh0; K = 64; rel = i - 6144;  baseS = 12288; }
  else if (i < 30720) { src = w_ih1; K = 64; rel = i - 18432; baseS = 36864; }
  else                { src = w_hh1; K = 64; rel = i - 30720; baseS = 61440; }
  int nks = K / 32;
  int fp   = rel >> 9;          // frag-pair id = ct*nks + ks
  int lane = (rel >> 3) & 63;
  int e    = rel & 7;
  int ct = fp / nks, ks = fp % nks;
  int g = ct * 16 + (lane & 15);
  int k = ks * 32 + (lane >> 4) * 8 + e;
  float v = src[g * K + k];
  unsigned int u = __float_as_uint(v);
  unsigned short hi = (unsigned short)(u >> 16);
  float hif = __uint_as_float(u & 0xFFFF0000u);
  unsigned short lo = (unsigned short)(__float_as_uint(v - hif) >> 16);
  int out = baseS + fp * 1024 + lane * 8 + e;
  wf[out]       = hi;
  wf[out + 512] = lo;
}

// --------------------------------------------------------------------------
// Layer 0: x[12][16384][32] -> ys0 (packed bf16 hi|lo u32) + z0 (fp32, t=11)
// Block = 256 thr (4 waves), 64 samples; wave w owns gate cols j=16w..16w+15
// (col-tiles {w, w+4, w+8} = r, z, n). 2 barriers per step.
// --------------------------------------------------------------------------
__global__ __launch_bounds__(256, 1) void gru_l0(
    const float* __restrict__ x, const unsigned short* __restrict__ wf,
    const float* __restrict__ b_ih, const float* __restrict__ b_hh,
    float* __restrict__ z0, unsigned int* __restrict__ ys0)
{
  __shared__ unsigned short wlds[36864];   // ih0 frags [0,12288) + hh0 [12288,36864)
  __shared__ unsigned int   hlds[64 * 68]; // packed h, row stride 68 u32
  const int tid = threadIdx.x;
  const int w = tid >> 6, l = tid & 63, lr = l & 15, lg = l >> 4;
  const int s0 = blockIdx.x * 64;
  const int j = w * 16 + lr;
  {
    const uint4* src = (const uint4*)wf;
    uint4* dst = (uint4*)wlds;
    for (int i = tid; i < 4608; i += 256) dst[i] = src[i];
    for (int i = tid; i < 4352; i += 256) hlds[i] = 0u;
  }
  const float br  = b_ih[j]      + b_hh[j];
  const float bz  = b_ih[64 + j] + b_hh[64 + j];
  const float bni = b_ih[128 + j];
  const float bnh = b_hh[128 + j];
  f32x4 vbr, vbz, vbni, vbnh;
  #pragma unroll
  for (int e = 0; e < 4; e++) { vbr[e] = br; vbz[e] = bz; vbni[e] = bni; vbnh[e] = bnh; }
  float hD[4][4];
  #pragma unroll
  for (int rt = 0; rt < 4; rt++)
    #pragma unroll
    for (int e = 0; e < 4; e++) hD[rt][e] = 0.f;
  __syncthreads();

  #pragma unroll 1
  for (int t = 0; t < SEQ; t++) {
    f32x4 aR[4], aZ[4], aNI[4], aNH[4];
    #pragma unroll
    for (int rt = 0; rt < 4; rt++) { aR[rt] = vbr; aZ[rt] = vbz; aNI[rt] = vbni; aNH[rt] = vbnh; }

    // prefetch X A-fragments (row = lr, k = lg*8..lg*8+7)
    float4 xa[4][2];
    #pragma unroll
    for (int rt = 0; rt < 4; rt++) {
      const float* xp = x + ((size_t)t * NBATCH + s0 + rt * 16 + lr) * FEAT + lg * 8;
      xa[rt][0] = *(const float4*)xp;
      xa[rt][1] = *(const float4*)(xp + 4);
    }
    // ---- ih0 (K=32, 1 kstep) ----
    {
      bf16x8 bRh = *(const bf16x8*)&wlds[(w    ) * 1024 + l * 8];
      bf16x8 bRl = *(const bf16x8*)&wlds[(w    ) * 1024 + 512 + l * 8];
      bf16x8 bZh = *(const bf16x8*)&wlds[(w + 4) * 1024 + l * 8];
      bf16x8 bZl = *(const bf16x8*)&wlds[(w + 4) * 1024 + 512 + l * 8];
      bf16x8 bNh = *(const bf16x8*)&wlds[(w + 8) * 1024 + l * 8];
      bf16x8 bNl = *(const bf16x8*)&wlds[(w + 8) * 1024 + 512 + l * 8];
      #pragma unroll
      for (int rt = 0; rt < 4; rt++) {
        bf16x8 Ah, Al;
        {
          B8u H, L;
          float fa[8] = {xa[rt][0].x, xa[rt][0].y, xa[rt][0].z, xa[rt][0].w,
                         xa[rt][1].x, xa[rt][1].y, xa[rt][1].z, xa[rt][1].w};
          #pragma unroll
          for (int i = 0; i < 8; i++) {
            unsigned int u = __float_as_uint(fa[i]);
            H.s[i] = (unsigned short)(u >> 16);
            float hf = __uint_as_float(u & 0xFFFF0000u);
            L.s[i] = (unsigned short)(__float_as_uint(fa[i] - hf) >> 16);
          }
          Ah = H.v; Al = L.v;
        }
        aR[rt]  = MFMA_B16(Ah, bRh, aR[rt]);  aR[rt]  = MFMA_B16(Al, bRh, aR[rt]);  aR[rt]  = MFMA_B16(Ah, bRl, aR[rt]);
        aZ[rt]  = MFMA_B16(Ah, bZh, aZ[rt]);  aZ[rt]  = MFMA_B16(Al, bZh, aZ[rt]);  aZ[rt]  = MFMA_B16(Ah, bZl, aZ[rt]);
        aNI[rt] = MFMA_B16(Ah, bNh, aNI[rt]); aNI[rt] = MFMA_B16(Al, bNh, aNI[rt]); aNI[rt] = MFMA_B16(Ah, bNl, aNI[rt]);
      }
    }
    // ---- hh0 (K=64, 2 ksteps), A from packed h in LDS ----
    #pragma unroll
    for (int ks = 0; ks < 2; ks++) {
      bf16x8 bRh = *(const bf16x8*)&wlds[12288 + ((w    ) * 2 + ks) * 1024 + l * 8];
      bf16x8 bRl = *(const bf16x8*)&wlds[12288 + ((w    ) * 2 + ks) * 1024 + 512 + l * 8];
      bf16x8 bZh = *(const bf16x8*)&wlds[12288 + ((w + 4) * 2 + ks) * 1024 + l * 8];
      bf16x8 bZl = *(const bf16x8*)&wlds[12288 + ((w + 4) * 2 + ks) * 1024 + 512 + l * 8];
      bf16x8 bNh = *(const bf16x8*)&wlds[12288 + ((w + 8) * 2 + ks) * 1024 + l * 8];
      bf16x8 bNl = *(const bf16x8*)&wlds[12288 + ((w + 8) * 2 + ks) * 1024 + 512 + l * 8];
      #pragma unroll
      for (int rt = 0; rt < 4; rt++) {
        const uint4 p0 = *(const uint4*)&hlds[(rt * 16 + lr) * 68 + ks * 32 + lg * 8];
        const uint4 p1 = *(const uint4*)&hlds[(rt * 16 + lr) * 68 + ks * 32 + lg * 8 + 4];
        bf16x8 Ah, Al;
        {
          B8u H, L;
          unsigned int pp[8] = {p0.x, p0.y, p0.z, p0.w, p1.x, p1.y, p1.z, p1.w};
          #pragma unroll
          for (int i = 0; i < 8; i++) {
            H.s[i] = (unsigned short)(pp[i] >> 16);
            L.s[i] = (unsigned short)(pp[i] & 0xFFFFu);
          }
          Ah = H.v; Al = L.v;
        }
        aR[rt]  = MFMA_B16(Ah, bRh, aR[rt]);  aR[rt]  = MFMA_B16(Al, bRh, aR[rt]);  aR[rt]  = MFMA_B16(Ah, bRl, aR[rt]);
        aZ[rt]  = MFMA_B16(Ah, bZh, aZ[rt]);  aZ[rt]  = MFMA_B16(Al, bZh, aZ[rt]);  aZ[rt]  = MFMA_B16(Ah, bZl, aZ[rt]);
        aNH[rt] = MFMA_B16(Ah, bNh, aNH[rt]); aNH[rt] = MFMA_B16(Al, bNh, aNH[rt]); aNH[rt] = MFMA_B16(Ah, bNl, aNH[rt]);
      }
    }
    __syncthreads();    // all h reads done before overwrite
    // ---- elementwise (D layout: row s = rt*16 + lg*4 + e, col j) ----
    #pragma unroll
    for (int rt = 0; rt < 4; rt++) {
      #pragma unroll
      for (int e = 0; e < 4; e++) {
        float rg = sigf(aR[rt][e]);
        float zg = sigf(aZ[rt][e]);
        float n  = tanh_fast(fmaf(rg, aNH[rt][e], aNI[rt][e]));
        float hn = fmaf(zg, hD[rt][e] - n, n);
        hD[rt][e] = hn;
        unsigned int uu = __float_as_uint(hn);
        unsigned int hi = uu & 0xFFFF0000u;
        unsigned int pk = hi | (__float_as_uint(hn - __uint_as_float(hi)) >> 16);
        int sl = rt * 16 + lg * 4 + e;
        hlds[sl * 68 + j] = pk;
        ys0[((size_t)t * NBATCH + s0 + sl) * 64 + j] = pk;
        if (t == SEQ - 1) z0[(size_t)(s0 + sl) * 64 + j] = hn;
      }
    }
    __syncthreads();    // new h visible before next step's reads
  }
}

// --------------------------------------------------------------------------
// Layer 1: ys0 (packed) -> z1 (fp32, t=11). Same structure, A(ih1) from global.
// --------------------------------------------------------------------------
__global__ __launch_bounds__(256, 1) void gru_l1(
    const unsigned int* __restrict__ ys0, const unsigned short* __restrict__ wf,
    const float* __restrict__ b_ih, const float* __restrict__ b_hh,
    float* __restrict__ z1)
{
  __shared__ unsigned short wlds[49152];   // ih1 [0,24576) + hh1 [24576,49152)
  __shared__ unsigned int   hlds[64 * 68];
  const int tid = threadIdx.x;
  const int w = tid >> 6, l = tid & 63, lr = l & 15, lg = l >> 4;
  const int s0 = blockIdx.x * 64;
  const int j = w * 16 + lr;
  {
    const uint4* src = (const uint4*)(wf + 36864);
    uint4* dst = (uint4*)wlds;
    for (int i = tid; i < 6144; i += 256) dst[i] = src[i];
    for (int i = tid; i < 4352; i += 256) hlds[i] = 0u;
  }
  const float br  = b_ih[j]      + b_hh[j];
  const float bz  = b_ih[64 + j] + b_hh[64 + j];
  const float bni = b_ih[128 + j];
  const float bnh = b_hh[128 + j];
  f32x4 vbr, vbz, vbni, vbnh;
  #pragma unroll
  for (int e = 0; e < 4; e++) { vbr[e] = br; vbz[e] = bz; vbni[e] = bni; vbnh[e] = bnh; }
  float hD[4][4];
  #pragma unroll
  for (int rt = 0; rt < 4; rt++)
    #pragma unroll
    for (int e = 0; e < 4; e++) hD[rt][e] = 0.f;
  __syncthreads();

  #pragma unroll 1
  for (int t = 0; t < SEQ; t++) {
    f32x4 aR[4], aZ[4], aNI[4], aNH[4];
    #pragma unroll
    for (int rt = 0; rt < 4; rt++) { aR[rt] = vbr; aZ[rt] = vbz; aNI[rt] = vbni; aNH[rt] = vbnh; }

    // prefetch ys0 A-fragments (packed)
    uint4 ya[2][4][2];
    #pragma unroll
    for (int ks = 0; ks < 2; ks++)
      #pragma unroll
      for (int rt = 0; rt < 4; rt++) {
        const unsigned int* yp = &ys0[((size_t)t * NBATCH + s0 + rt * 16 + lr) * 64 + ks * 32 + lg * 8];
        ya[ks][rt][0] = *(const uint4*)yp;
        ya[ks][rt][1] = *(const uint4*)(yp + 4);
      }
    // ---- ih1 (K=64), A = ys0 ----
    #pragma unroll
    for (int ks = 0; ks < 2; ks++) {
      bf16x8 bRh = *(const bf16x8*)&wlds[((w    ) * 2 + ks) * 1024 + l * 8];
      bf16x8 bRl = *(const bf16x8*)&wlds[((w    ) * 2 + ks) * 1024 + 512 + l * 8];
      bf16x8 bZh = *(const bf16x8*)&wlds[((w + 4) * 2 + ks) * 1024 + l * 8];
      bf16x8 bZl = *(const bf16x8*)&wlds[((w + 4) * 2 + ks) * 1024 + 512 + l * 8];
      bf16x8 bNh = *(const bf16x8*)&wlds[((w + 8) * 2 + ks) * 1024 + l * 8];
      bf16x8 bNl = *(const bf16x8*)&wlds[((w + 8) * 2 + ks) * 1024 + 512 + l * 8];
      #pragma unroll
      for (int rt = 0; rt < 4; rt++) {
        bf16x8 Ah, Al;
        {
          B8u H, L;
          unsigned int pp[8] = {ya[ks][rt][0].x, ya[ks][rt][0].y, ya[ks][rt][0].z, ya[ks][rt][0].w,
                                ya[ks][rt][1].x, ya[ks][rt][1].y, ya[ks][rt][1].z, ya[ks][rt][1].w};
          #pragma unroll
          for (int i = 0; i < 8; i++) {
            H.s[i] = (unsigned short)(pp[i] >> 16);
            L.s[i] = (unsigned short)(pp[i] & 0xFFFFu);
          }
          Ah = H.v; Al = L.v;
        }
        aR[rt]  = MFMA_B16(Ah, bRh, aR[rt]);  aR[rt]  = MFMA_B16(Al, bRh, aR[rt]);  aR[rt]  = MFMA_B16(Ah, bRl, aR[rt]);
        aZ[rt]  = MFMA_B16(Ah, bZh, aZ[rt]);  aZ[rt]  = MFMA_B16(Al, bZh, aZ[rt]);  aZ[rt]  = MFMA_B16(Ah, bZl, aZ[rt]);
        aNI[rt] = MFMA_B16(Ah, bNh, aNI[rt]); aNI[rt] = MFMA_B16(Al, bNh, aNI[rt]); aNI[rt] = MFMA_B16(Ah, bNl, aNI[rt]);
      }
    }
    // ---- hh1 (K=64), A = packed h1 in LDS ----
    #pragma unroll
    for (int ks = 0; ks < 2; ks++) {
      bf16x8 bRh = *(const bf16x8*)&wlds[24576 + ((w    ) * 2 + ks) * 1024 + l * 8];
      bf16x8 bRl = *(const bf16x8*)&wlds[24576 + ((w    ) * 2 + ks) * 1024 + 512 + l * 8];
      bf16x8 bZh = *(const bf16x8*)&wlds[24576 + ((w + 4) * 2 + ks) * 1024 + l * 8];
      bf16x8 bZl = *(const bf16x8*)&wlds[24576 + ((w + 4) * 2 + ks) * 1024 + 512 + l * 8];
      bf16x8 bNh = *(const bf16x8*)&wlds[24576 + ((w + 8) * 2 + ks) * 1024 + l * 8];
      bf16x8 bNl = *(const bf16x8*)&wlds[24576 + ((w + 8) * 2 + ks) * 1024 + 512 + l * 8];
      #pragma unroll
      for (int rt = 0; rt < 4; rt++) {
        const uint4 p0 = *(const uint4*)&hlds[(rt * 16 + lr) * 68 + ks * 32 + lg * 8];
        const uint4 p1 = *(const uint4*)&hlds[(rt * 16 + lr) * 68 + ks * 32 + lg * 8 + 4];
        bf16x8 Ah, Al;
        {
          B8u H, L;
          unsigned int pp[8] = {p0.x, p0.y, p0.z, p0.w, p1.x, p1.y, p1.z, p1.w};
          #pragma unroll
          for (int i = 0; i < 8; i++) {
            H.s[i] = (unsigned short)(pp[i] >> 16);
            L.s[i] = (unsigned short)(pp[i] & 0xFFFFu);
          }
          Ah = H.v; Al = L.v;
        }
        aR[rt]  = MFMA_B16(Ah, bRh, aR[rt]);  aR[rt]  = MFMA_B16(Al, bRh, aR[rt]);  aR[rt]  = MFMA_B16(Ah, bRl, aR[rt]);
        aZ[rt]  = MFMA_B16(Ah, bZh, aZ[rt]);  aZ[rt]  = MFMA_B16(Al, bZh, aZ[rt]);  aZ[rt]  = MFMA_B16(Ah, bZl, aZ[rt]);
        aNH[rt] = MFMA_B16(Ah, bNh, aNH[rt]); aNH[rt] = MFMA_B16(Al, bNh, aNH[rt]); aNH[rt] = MFMA_B16(Ah, bNl, aNH[rt]);
      }
    }
    __syncthreads();
    #pragma unroll
    for (int rt = 0; rt < 4; rt++) {
      #pragma unroll
      for (int e = 0; e < 4; e++) {
        float rg = sigf(aR[rt][e]);
        float zg = sigf(aZ[rt][e]);
        float n  = tanh_fast(fmaf(rg, aNH[rt][e], aNI[rt][e]));
        float hn = fmaf(zg, hD[rt][e] - n, n);
        hD[rt][e] = hn;
        unsigned int uu = __float_as_uint(hn);
        unsigned int hi = uu & 0xFFFF0000u;
        unsigned int pk = hi | (__float_as_uint(hn - __uint_as_float(hi)) >> 16);
        int sl = rt * 16 + lg * 4 + e;
        hlds[sl * 68 + j] = pk;
        if (t == SEQ - 1) z1[(size_t)(s0 + sl) * 64 + j] = hn;
      }
    }
    __syncthreads();
  }
}

// ===========================================================================
// FALLBACK (small ws): round-2 LDS-weight GRU (verified, 455us) + fp32 pack
// ===========================================================================
__global__ void prep_kernel(const float* __restrict__ w_ih0, const float* __restrict__ w_hh0,
                            const float* __restrict__ w_ih1, const float* __restrict__ w_hh1,
                            float* __restrict__ wp)
{
  for (int i = blockIdx.x * blockDim.x + threadIdx.x; i < WP_TOTAL; i += gridDim.x * blockDim.x) {
    const float* src;
    int K, rel;
    if (i < WP_HH0)      { src = w_ih0; K = 32; rel = i; }
    else if (i < WP_IH1) { src = w_hh0; K = 64; rel = i - WP_HH0; }
    else if (i < WP_HH1) { src = w_ih1; K = 64; rel = i - WP_IH1; }
    else                 { src = w_hh1; K = 64; rel = i - WP_HH1; }
    int kr = rel & 3;
    int jj = (rel >> 2) & 63;
    int rest = rel >> 8;
    int g = rest % 3;
    int k4 = rest / 3;
    wp[i] = src[(g * 64 + jj) * K + k4 * 4 + kr];
  }
}

__global__ __launch_bounds__(256, 1) void gru_fallback(
    const float* __restrict__ x, const float* __restrict__ wpack,
    const float* __restrict__ b_ih0, const float* __restrict__ b_hh0,
    const float* __restrict__ b_ih1, const float* __restrict__ b_hh1,
    float* __restrict__ zout)
{
  __shared__ float wlds[36864];
  __shared__ float h0s[16][64];
  __shared__ float h1s[16][64];
  const int tid = threadIdx.x;
  {
    const float4* src = (const float4*)(wpack + WP_HH0);
    float4* dst = (float4*)wlds;
    #pragma unroll 4
    for (int i = tid; i < 9216; i += 256) dst[i] = src[i];
  }
  const int j  = tid & 63;
  const int sg = __builtin_amdgcn_readfirstlane(tid >> 6);
  const float br0  = b_ih0[j]      + b_hh0[j];
  const float bz0  = b_ih0[64 + j] + b_hh0[64 + j];
  const float bni0 = b_ih0[128 + j];
  const float bnh0 = b_hh0[128 + j];
  const float br1  = b_ih1[j]      + b_hh1[j];
  const float bz1  = b_ih1[64 + j] + b_hh1[64 + j];
  const float bni1 = b_ih1[128 + j];
  const float bnh1 = b_hh1[128 + j];
  const int s0 = blockIdx.x * 16;
  float h0r[4] = {0.f, 0.f, 0.f, 0.f};
  float h1r[4] = {0.f, 0.f, 0.f, 0.f};
  #pragma unroll
  for (int ss = 0; ss < 4; ss++) { h0s[sg * 4 + ss][j] = 0.f; h1s[sg * 4 + ss][j] = 0.f; }
  __syncthreads();
  const float4* wih0g = (const float4*)(wpack + WP_IH0);
  const float4* whh0l = (const float4*)(wlds);
  const float4* wih1l = (const float4*)(wlds + 12288);
  const float4* whh1l = (const float4*)(wlds + 24576);
  for (int t = 0; t < SEQ; t++) {
    float ar[4], az[4], ani[4], anh[4];
    #pragma unroll
    for (int ss = 0; ss < 4; ss++) { ar[ss] = br0; az[ss] = bz0; ani[ss] = bni0; anh[ss] = bnh0; }
    const float4* xr0 = (const float4*)(x + ((size_t)t * NBATCH + (s0 + sg * 4 + 0)) * FEAT);
    const float4* xr1 = (const float4*)(x + ((size_t)t * NBATCH + (s0 + sg * 4 + 1)) * FEAT);
    const float4* xr2 = (const float4*)(x + ((size_t)t * NBATCH + (s0 + sg * 4 + 2)) * FEAT);
    const float4* xr3 = (const float4*)(x + ((size_t)t * NBATCH + (s0 + sg * 4 + 3)) * FEAT);
    #pragma unroll
    for (int k4 = 0; k4 < 8; k4++) {
      float4 wr = wih0g[(k4 * 3 + 0) * 64 + j];
      float4 wz = wih0g[(k4 * 3 + 1) * 64 + j];
      float4 wn = wih0g[(k4 * 3 + 2) * 64 + j];
      float4 xv[4] = {xr0[k4], xr1[k4], xr2[k4], xr3[k4]};
      #pragma unroll
      for (int ss = 0; ss < 4; ss++) {
        DOT4(ar[ss],  wr, xv[ss]);
        DOT4(az[ss],  wz, xv[ss]);
        DOT4(ani[ss], wn, xv[ss]);
      }
    }
    #pragma unroll
    for (int k4 = 0; k4 < 16; k4++) {
      float4 wr = whh0l[(k4 * 3 + 0) * 64 + j];
      float4 wz = whh0l[(k4 * 3 + 1) * 64 + j];
      float4 wn = whh0l[(k4 * 3 + 2) * 64 + j];
      #pragma unroll
      for (int ss = 0; ss < 4; ss++) {
        float4 hv = *(const float4*)&h0s[sg * 4 + ss][k4 * 4];
        DOT4(ar[ss],  wr, hv);
        DOT4(az[ss],  wz, hv);
        DOT4(anh[ss], wn, hv);
      }
    }
    float h0n[4];
    #pragma unroll
    for (int ss = 0; ss < 4; ss++) {
      float rg = sigf(ar[ss]);
      float zg = sigf(az[ss]);
      float ng = tanh_fast(fmaf(rg, anh[ss], ani[ss]));
      h0n[ss] = fmaf(zg, h0r[ss] - ng, ng);
    }
    __syncthreads();
    #pragma unroll
    for (int ss = 0; ss < 4; ss++) { h0s[sg * 4 + ss][j] = h0n[ss]; h0r[ss] = h0n[ss]; }
    __syncthreads();
    #pragma unroll
    for (int ss = 0; ss < 4; ss++) { ar[ss] = br1; az[ss] = bz1; ani[ss] = bni1; anh[ss] = bnh1; }
    #pragma unroll
    for (int k4 = 0; k4 < 16; k4++) {
      float4 wr = wih1l[(k4 * 3 + 0) * 64 + j];
      float4 wz = wih1l[(k4 * 3 + 1) * 64 + j];
      float4 wn = wih1l[(k4 * 3 + 2) * 64 + j];
      #pragma unroll
      for (int ss = 0; ss < 4; ss++) {
        float4 hv = *(const float4*)&h0s[sg * 4 + ss][k4 * 4];
        DOT4(ar[ss],  wr, hv);
        DOT4(az[ss],  wz, hv);
        DOT4(ani[ss], wn, hv);
      }
    }
    #pragma unroll
    for (int k4 = 0; k4 < 16; k4++) {
      float4 wr = whh1l[(k4 * 3 + 0) * 64 + j];
      float4 wz = whh1l[(k4 * 3 + 1) * 64 + j];
      float4 wn = whh1l[(k4 * 3 + 2) * 64 + j];
      #pragma unroll
      for (int ss = 0; ss < 4; ss++) {
        float4 hv = *(const float4*)&h1s[sg * 4 + ss][k4 * 4];
        DOT4(ar[ss],  wr, hv);
        DOT4(az[ss],  wz, hv);
        DOT4(anh[ss], wn, hv);
      }
    }
    float h1n[4];
    #pragma unroll
    for (int ss = 0; ss < 4; ss++) {
      float rg = sigf(ar[ss]);
      float zg = sigf(az[ss]);
      float ng = tanh_fast(fmaf(rg, anh[ss], ani[ss]));
      h1n[ss] = fmaf(zg, h1r[ss] - ng, ng);
    }
    __syncthreads();
    #pragma unroll
    for (int ss = 0; ss < 4; ss++) { h1s[sg * 4 + ss][j] = h1n[ss]; h1r[ss] = h1n[ss]; }
    __syncthreads();
  }
  #pragma unroll
  for (int ss = 0; ss < 4; ss++) {
    int s = s0 + sg * 4 + ss;
    zout[(size_t)s * 64 + j]            = h0r[ss];
    zout[(size_t)(NBATCH + s) * 64 + j] = h1r[ss];
  }
}

// ---------------------------------------------------------------------------
// GAT: flash-style fused attention (round-3 conflict-free mapping, verified).
// ---------------------------------------------------------------------------
__global__ __launch_bounds__(256, 3) void gat_kernel(const float* __restrict__ z,
                                                     const int* __restrict__ mask,
                                                     float* __restrict__ out)
{
  __shared__ float Q [64][68];
  __shared__ float Kt[64][68];
  __shared__ float P [64][68];
  const int tid = threadIdx.x;
  const int rt = blockIdx.x & 15;
  const int lb = blockIdx.x >> 4;
  const float* zb = z + (size_t)lb * 1024 * 64;
  const int n0 = rt * 64;
  for (int i = tid; i < 1024; i += 256) {
    int row = i >> 4, c4 = i & 15;
    *(float4*)&Q[row][c4 * 4] = ((const float4*)(zb + (size_t)(n0 + row) * 64))[c4];
  }
  const int r = tid >> 4, c = tid & 15;
  float O[4][4];
  float Mr[4], Dr[4];
  #pragma unroll
  for (int a = 0; a < 4; a++) {
    Mr[a] = -INFINITY; Dr[a] = 0.f;
    #pragma unroll
    for (int b2 = 0; b2 < 4; b2++) O[a][b2] = 0.f;
  }
  for (int mt = 0; mt < 16; mt++) {
    __syncthreads();
    for (int i = tid; i < 1024; i += 256) {
      int row = i >> 4, c4 = i & 15;
      *(float4*)&Kt[row][c4 * 4] = ((const float4*)(zb + (size_t)(mt * 64 + row) * 64))[c4];
    }
    __syncthreads();
    float S[4][4];
    #pragma unroll
    for (int a = 0; a < 4; a++)
      #pragma unroll
      for (int b2 = 0; b2 < 4; b2++) S[a][b2] = 0.f;
    #pragma unroll
    for (int k4 = 0; k4 < 16; k4++) {
      float4 q0 = *(const float4*)&Q[r + 16 * 0][k4 * 4];
      float4 q1 = *(const float4*)&Q[r + 16 * 1][k4 * 4];
      float4 q2 = *(const float4*)&Q[r + 16 * 2][k4 * 4];
      float4 q3 = *(const float4*)&Q[r + 16 * 3][k4 * 4];
      float4 k0 = *(const float4*)&Kt[c + 16 * 0][k4 * 4];
      float4 k1 = *(const float4*)&Kt[c + 16 * 1][k4 * 4];
      float4 k2 = *(const float4*)&Kt[c + 16 * 2][k4 * 4];
      float4 k3 = *(const float4*)&Kt[c + 16 * 3][k4 * 4];
      DOT4(S[0][0], q0, k0); DOT4(S[0][1], q0, k1); DOT4(S[0][2], q0, k2); DOT4(S[0][3], q0, k3);
      DOT4(S[1][0], q1, k0); DOT4(S[1][1], q1, k1); DOT4(S[1][2], q1, k2); DOT4(S[1][3], q1, k3);
      DOT4(S[2][0], q2, k0); DOT4(S[2][1], q2, k1); DOT4(S[2][2], q2, k2); DOT4(S[2][3], q2, k3);
      DOT4(S[3][0], q3, k0); DOT4(S[3][1], q3, k1); DOT4(S[3][2], q3, k2); DOT4(S[3][3], q3, k3);
    }
    #pragma unroll
    for (int ri = 0; ri < 4; ri++) {
      #pragma unroll
      for (int ci = 0; ci < 4; ci++) {
        int mm = mask[(size_t)(n0 + r + 16 * ri) * 1024 + mt * 64 + c + 16 * ci];
        float v = S[ri][ci];
        float lr = v > 0.f ? v : 0.1f * v;
        float a = mm ? lr : 0.f;
        S[ri][ci] = (a == 0.f) ? -1e16f : a;
      }
    }
    #pragma unroll
    for (int ri = 0; ri < 4; ri++) {
      float m = fmaxf(fmaxf(S[ri][0], S[ri][1]), fmaxf(S[ri][2], S[ri][3]));
      #pragma unroll
      for (int w = 1; w < 16; w <<= 1) m = fmaxf(m, __shfl_xor(m, w, 16));
      float newM = fmaxf(Mr[ri], m);
      float sc = __expf(Mr[ri] - newM);
      float ps = 0.f;
      #pragma unroll
      for (int ci = 0; ci < 4; ci++) {
        float p = __expf(S[ri][ci] - newM);
        S[ri][ci] = p;
        ps += p;
      }
      #pragma unroll
      for (int w = 1; w < 16; w <<= 1) ps += __shfl_xor(ps, w, 16);
      Dr[ri] = Dr[ri] * sc + ps;
      Mr[ri] = newM;
      #pragma unroll
      for (int ci = 0; ci < 4; ci++) O[ri][ci] *= sc;
      #pragma unroll
      for (int ci = 0; ci < 4; ci++) P[r + 16 * ri][c + 16 * ci] = S[ri][ci];
    }
    #pragma unroll
    for (int m4 = 0; m4 < 16; m4++) {
      float4 v0 = *(const float4*)&Kt[m4 * 4 + 0][c * 4];
      float4 v1 = *(const float4*)&Kt[m4 * 4 + 1][c * 4];
      float4 v2 = *(const float4*)&Kt[m4 * 4 + 2][c * 4];
      float4 v3 = *(const float4*)&Kt[m4 * 4 + 3][c * 4];
      #pragma unroll
      for (int ri = 0; ri < 4; ri++) {
        float4 p4 = *(const float4*)&P[r + 16 * ri][m4 * 4];
        O[ri][0] = fmaf(p4.x, v0.x, O[ri][0]); O[ri][1] = fmaf(p4.x, v0.y, O[ri][1]);
        O[ri][2] = fmaf(p4.x, v0.z, O[ri][2]); O[ri][3] = fmaf(p4.x, v0.w, O[ri][3]);
        O[ri][0] = fmaf(p4.y, v1.x, O[ri][0]); O[ri][1] = fmaf(p4.y, v1.y, O[ri][1]);
        O[ri][2] = fmaf(p4.y, v1.z, O[ri][2]); O[ri][3] = fmaf(p4.y, v1.w, O[ri][3]);
        O[ri][0] = fmaf(p4.z, v2.x, O[ri][0]); O[ri][1] = fmaf(p4.z, v2.y, O[ri][1]);
        O[ri][2] = fmaf(p4.z, v2.z, O[ri][2]); O[ri][3] = fmaf(p4.z, v2.w, O[ri][3]);
        O[ri][0] = fmaf(p4.w, v3.x, O[ri][0]); O[ri][1] = fmaf(p4.w, v3.y, O[ri][1]);
        O[ri][2] = fmaf(p4.w, v3.z, O[ri][2]); O[ri][3] = fmaf(p4.w, v3.w, O[ri][3]);
      }
    }
  }
  #pragma unroll
  for (int ri = 0; ri < 4; ri++) {
    float inv = 1.0f / Dr[ri];
    float4 o4 = make_float4(O[ri][0] * inv, O[ri][1] * inv, O[ri][2] * inv, O[ri][3] * inv);
    *(float4*)(out + ((size_t)lb * 1024 + n0 + r + 16 * ri) * 64 + c * 4) = o4;
  }
}

extern "C" void kernel_launch(void* const* d_in, const int* in_sizes, int n_in,
                              void* d_out, int out_size, void* d_ws, size_t ws_size,
                              hipStream_t stream) {
  const float* h     = (const float*)d_in[0];
  const int*   mask  = (const int*)d_in[1];
  const float* w_ih0 = (const float*)d_in[2];
  const float* w_hh0 = (const float*)d_in[3];
  const float* b_ih0 = (const float*)d_in[4];
  const float* b_hh0 = (const float*)d_in[5];
  const float* w_ih1 = (const float*)d_in[6];
  const float* w_hh1 = (const float*)d_in[7];
  const float* b_ih1 = (const float*)d_in[8];
  const float* b_hh1 = (const float*)d_in[9];
  float* out = (float*)d_out;

  char* wsb = (char*)d_ws;
  float* zws = (float*)wsb;                                   // [2][16384][64] fp32
  const size_t Z_BYTES  = (size_t)2 * NBATCH * 64 * 4;        // 8388608
  const size_t YS_OFF   = Z_BYTES + 176128;                   // aligned past 172KB frag weights
  const size_t NEED_FAST = YS_OFF + (size_t)SEQ * NBATCH * 64 * 4;

  if (ws_size >= NEED_FAST) {
    unsigned short* wfrag = (unsigned short*)(wsb + Z_BYTES);
    unsigned int*   ys0   = (unsigned int*)(wsb + YS_OFF);
    prep_frag_kernel<<<168, 256, 0, stream>>>(w_ih0, w_hh0, w_ih1, w_hh1, wfrag);
    gru_l0<<<256, 256, 0, stream>>>(h, wfrag, b_ih0, b_hh0, zws, ys0);
    gru_l1<<<256, 256, 0, stream>>>(ys0, wfrag, b_ih1, b_hh1, zws + (size_t)NBATCH * 64);
  } else {
    float* wpack = (float*)(wsb + Z_BYTES);
    prep_kernel<<<24, 256, 0, stream>>>(w_ih0, w_hh0, w_ih1, w_hh1, wpack);
    gru_fallback<<<1024, 256, 0, stream>>>(h, wpack, b_ih0, b_hh0, b_ih1, b_hh1, zws);
  }
  gat_kernel<<<512, 256, 0, stream>>>(zws, mask, out);
}

// Round 5
// 253.185 us; speedup vs baseline: 5.6843x; 1.2054x over previous
//
#include <hip/hip_runtime.h>
#include <math.h>

#define SEQ 12
#define NBATCH 16384   // BC*NODES
#define FEAT 32
#define HID 64

// ---- fallback packed-weight layout (floats, round-2 format) ----
#define WP_IH0 0
#define WP_HH0 6144
#define WP_IH1 18432
#define WP_HH1 30720
#define WP_TOTAL 43008

typedef __attribute__((ext_vector_type(8))) short bf16x8;   // 8 bf16 = 4 VGPR
typedef __attribute__((ext_vector_type(4))) float f32x4;

#define MFMA_B16(A,B,C) __builtin_amdgcn_mfma_f32_16x16x32_bf16((A),(B),(C),0,0,0)

union B8u { unsigned short s[8]; bf16x8 v; };

__device__ __forceinline__ float sigf(float x) { return 1.0f / (1.0f + __expf(-x)); }
__device__ __forceinline__ float tanh_fast(float x) { return 2.0f / (1.0f + __expf(-2.0f * x)) - 1.0f; }

__device__ __forceinline__ unsigned int packsplit(float v) {
  unsigned int u  = __float_as_uint(v);
  unsigned int hi = u & 0xFFFF0000u;
  unsigned int lo = __float_as_uint(v - __uint_as_float(hi)) >> 16;
  return hi | lo;
}

__device__ __forceinline__ void unpack8(const unsigned int* p, bf16x8& H, bf16x8& L) {
  uint4 u0 = *(const uint4*)p;
  uint4 u1 = *(const uint4*)(p + 4);
  unsigned int uu[8] = {u0.x, u0.y, u0.z, u0.w, u1.x, u1.y, u1.z, u1.w};
  B8u hh, ll;
  #pragma unroll
  for (int i = 0; i < 8; i++) {
    hh.s[i] = (unsigned short)(uu[i] >> 16);
    ll.s[i] = (unsigned short)(uu[i] & 0xFFFFu);
  }
  H = hh.v; L = ll.v;
}

#define DOT4(acc, A_, B_)                                   \
  acc = fmaf((A_).x, (B_).x, acc);                          \
  acc = fmaf((A_).y, (B_).y, acc);                          \
  acc = fmaf((A_).z, (B_).z, acc);                          \
  acc = fmaf((A_).w, (B_).w, acc);

// ===========================================================================
// MFMA GRU (verified round 4).
// ===========================================================================
__global__ void prep_frag_kernel(const float* __restrict__ w_ih0, const float* __restrict__ w_hh0,
                                 const float* __restrict__ w_ih1, const float* __restrict__ w_hh1,
                                 unsigned short* __restrict__ wf)
{
  int i = blockIdx.x * blockDim.x + threadIdx.x;   // 0..43007
  if (i >= 43008) return;
  const float* src; int K, rel, baseS;
  if (i < 6144)       { src = w_ih0; K = 32; rel = i;         baseS = 0; }
  else if (i < 18432) { src = w_hh0; K = 64; rel = i - 6144;  baseS = 12288; }
  else if (i < 30720) { src = w_ih1; K = 64; rel = i - 18432; baseS = 36864; }
  else                { src = w_hh1; K = 64; rel = i - 30720; baseS = 61440; }
  int nks = K / 32;
  int fp   = rel >> 9;
  int lane = (rel >> 3) & 63;
  int e    = rel & 7;
  int ct = fp / nks, ks = fp % nks;
  int g = ct * 16 + (lane & 15);
  int k = ks * 32 + (lane >> 4) * 8 + e;
  float v = src[g * K + k];
  unsigned int u = __float_as_uint(v);
  unsigned short hi = (unsigned short)(u >> 16);
  float hif = __uint_as_float(u & 0xFFFF0000u);
  unsigned short lo = (unsigned short)(__float_as_uint(v - hif) >> 16);
  int out = baseS + fp * 1024 + lane * 8 + e;
  wf[out]       = hi;
  wf[out + 512] = lo;
}

__global__ __launch_bounds__(256, 1) void gru_l0(
    const float* __restrict__ x, const unsigned short* __restrict__ wf,
    const float* __restrict__ b_ih, const float* __restrict__ b_hh,
    float* __restrict__ z0, unsigned int* __restrict__ ys0)
{
  __shared__ unsigned short wlds[36864];
  __shared__ unsigned int   hlds[64 * 68];
  const int tid = threadIdx.x;
  const int w = tid >> 6, l = tid & 63, lr = l & 15, lg = l >> 4;
  const int s0 = blockIdx.x * 64;
  const int j = w * 16 + lr;
  {
    const uint4* src = (const uint4*)wf;
    uint4* dst = (uint4*)wlds;
    for (int i = tid; i < 4608; i += 256) dst[i] = src[i];
    for (int i = tid; i < 4352; i += 256) hlds[i] = 0u;
  }
  const float br  = b_ih[j]      + b_hh[j];
  const float bz  = b_ih[64 + j] + b_hh[64 + j];
  const float bni = b_ih[128 + j];
  const float bnh = b_hh[128 + j];
  f32x4 vbr, vbz, vbni, vbnh;
  #pragma unroll
  for (int e = 0; e < 4; e++) { vbr[e] = br; vbz[e] = bz; vbni[e] = bni; vbnh[e] = bnh; }
  float hD[4][4];
  #pragma unroll
  for (int rt = 0; rt < 4; rt++)
    #pragma unroll
    for (int e = 0; e < 4; e++) hD[rt][e] = 0.f;
  __syncthreads();

  #pragma unroll 1
  for (int t = 0; t < SEQ; t++) {
    f32x4 aR[4], aZ[4], aNI[4], aNH[4];
    #pragma unroll
    for (int rt = 0; rt < 4; rt++) { aR[rt] = vbr; aZ[rt] = vbz; aNI[rt] = vbni; aNH[rt] = vbnh; }

    float4 xa[4][2];
    #pragma unroll
    for (int rt = 0; rt < 4; rt++) {
      const float* xp = x + ((size_t)t * NBATCH + s0 + rt * 16 + lr) * FEAT + lg * 8;
      xa[rt][0] = *(const float4*)xp;
      xa[rt][1] = *(const float4*)(xp + 4);
    }
    {
      bf16x8 bRh = *(const bf16x8*)&wlds[(w    ) * 1024 + l * 8];
      bf16x8 bRl = *(const bf16x8*)&wlds[(w    ) * 1024 + 512 + l * 8];
      bf16x8 bZh = *(const bf16x8*)&wlds[(w + 4) * 1024 + l * 8];
      bf16x8 bZl = *(const bf16x8*)&wlds[(w + 4) * 1024 + 512 + l * 8];
      bf16x8 bNh = *(const bf16x8*)&wlds[(w + 8) * 1024 + l * 8];
      bf16x8 bNl = *(const bf16x8*)&wlds[(w + 8) * 1024 + 512 + l * 8];
      #pragma unroll
      for (int rt = 0; rt < 4; rt++) {
        bf16x8 Ah, Al;
        {
          B8u H, L;
          float fa[8] = {xa[rt][0].x, xa[rt][0].y, xa[rt][0].z, xa[rt][0].w,
                         xa[rt][1].x, xa[rt][1].y, xa[rt][1].z, xa[rt][1].w};
          #pragma unroll
          for (int i = 0; i < 8; i++) {
            unsigned int u = __float_as_uint(fa[i]);
            H.s[i] = (unsigned short)(u >> 16);
            float hf = __uint_as_float(u & 0xFFFF0000u);
            L.s[i] = (unsigned short)(__float_as_uint(fa[i] - hf) >> 16);
          }
          Ah = H.v; Al = L.v;
        }
        aR[rt]  = MFMA_B16(Ah, bRh, aR[rt]);  aR[rt]  = MFMA_B16(Al, bRh, aR[rt]);  aR[rt]  = MFMA_B16(Ah, bRl, aR[rt]);
        aZ[rt]  = MFMA_B16(Ah, bZh, aZ[rt]);  aZ[rt]  = MFMA_B16(Al, bZh, aZ[rt]);  aZ[rt]  = MFMA_B16(Ah, bZl, aZ[rt]);
        aNI[rt] = MFMA_B16(Ah, bNh, aNI[rt]); aNI[rt] = MFMA_B16(Al, bNh, aNI[rt]); aNI[rt] = MFMA_B16(Ah, bNl, aNI[rt]);
      }
    }
    #pragma unroll
    for (int ks = 0; ks < 2; ks++) {
      bf16x8 bRh = *(const bf16x8*)&wlds[12288 + ((w    ) * 2 + ks) * 1024 + l * 8];
      bf16x8 bRl = *(const bf16x8*)&wlds[12288 + ((w    ) * 2 + ks) * 1024 + 512 + l * 8];
      bf16x8 bZh = *(const bf16x8*)&wlds[12288 + ((w + 4) * 2 + ks) * 1024 + l * 8];
      bf16x8 bZl = *(const bf16x8*)&wlds[12288 + ((w + 4) * 2 + ks) * 1024 + 512 + l * 8];
      bf16x8 bNh = *(const bf16x8*)&wlds[12288 + ((w + 8) * 2 + ks) * 1024 + l * 8];
      bf16x8 bNl = *(const bf16x8*)&wlds[12288 + ((w + 8) * 2 + ks) * 1024 + 512 + l * 8];
      #pragma unroll
      for (int rt = 0; rt < 4; rt++) {
        const uint4 p0 = *(const uint4*)&hlds[(rt * 16 + lr) * 68 + ks * 32 + lg * 8];
        const uint4 p1 = *(const uint4*)&hlds[(rt * 16 + lr) * 68 + ks * 32 + lg * 8 + 4];
        bf16x8 Ah, Al;
        {
          B8u H, L;
          unsigned int pp[8] = {p0.x, p0.y, p0.z, p0.w, p1.x, p1.y, p1.z, p1.w};
          #pragma unroll
          for (int i = 0; i < 8; i++) {
            H.s[i] = (unsigned short)(pp[i] >> 16);
            L.s[i] = (unsigned short)(pp[i] & 0xFFFFu);
          }
          Ah = H.v; Al = L.v;
        }
        aR[rt]  = MFMA_B16(Ah, bRh, aR[rt]);  aR[rt]  = MFMA_B16(Al, bRh, aR[rt]);  aR[rt]  = MFMA_B16(Ah, bRl, aR[rt]);
        aZ[rt]  = MFMA_B16(Ah, bZh, aZ[rt]);  aZ[rt]  = MFMA_B16(Al, bZh, aZ[rt]);  aZ[rt]  = MFMA_B16(Ah, bZl, aZ[rt]);
        aNH[rt] = MFMA_B16(Ah, bNh, aNH[rt]); aNH[rt] = MFMA_B16(Al, bNh, aNH[rt]); aNH[rt] = MFMA_B16(Ah, bNl, aNH[rt]);
      }
    }
    __syncthreads();
    #pragma unroll
    for (int rt = 0; rt < 4; rt++) {
      #pragma unroll
      for (int e = 0; e < 4; e++) {
        float rg = sigf(aR[rt][e]);
        float zg = sigf(aZ[rt][e]);
        float n  = tanh_fast(fmaf(rg, aNH[rt][e], aNI[rt][e]));
        float hn = fmaf(zg, hD[rt][e] - n, n);
        hD[rt][e] = hn;
        unsigned int uu = __float_as_uint(hn);
        unsigned int hi = uu & 0xFFFF0000u;
        unsigned int pk = hi | (__float_as_uint(hn - __uint_as_float(hi)) >> 16);
        int sl = rt * 16 + lg * 4 + e;
        hlds[sl * 68 + j] = pk;
        ys0[((size_t)t * NBATCH + s0 + sl) * 64 + j] = pk;
        if (t == SEQ - 1) z0[(size_t)(s0 + sl) * 64 + j] = hn;
      }
    }
    __syncthreads();
  }
}

__global__ __launch_bounds__(256, 1) void gru_l1(
    const unsigned int* __restrict__ ys0, const unsigned short* __restrict__ wf,
    const float* __restrict__ b_ih, const float* __restrict__ b_hh,
    float* __restrict__ z1)
{
  __shared__ unsigned short wlds[49152];
  __shared__ unsigned int   hlds[64 * 68];
  const int tid = threadIdx.x;
  const int w = tid >> 6, l = tid & 63, lr = l & 15, lg = l >> 4;
  const int s0 = blockIdx.x * 64;
  const int j = w * 16 + lr;
  {
    const uint4* src = (const uint4*)(wf + 36864);
    uint4* dst = (uint4*)wlds;
    for (int i = tid; i < 6144; i += 256) dst[i] = src[i];
    for (int i = tid; i < 4352; i += 256) hlds[i] = 0u;
  }
  const float br  = b_ih[j]      + b_hh[j];
  const float bz  = b_ih[64 + j] + b_hh[64 + j];
  const float bni = b_ih[128 + j];
  const float bnh = b_hh[128 + j];
  f32x4 vbr, vbz, vbni, vbnh;
  #pragma unroll
  for (int e = 0; e < 4; e++) { vbr[e] = br; vbz[e] = bz; vbni[e] = bni; vbnh[e] = bnh; }
  float hD[4][4];
  #pragma unroll
  for (int rt = 0; rt < 4; rt++)
    #pragma unroll
    for (int e = 0; e < 4; e++) hD[rt][e] = 0.f;
  __syncthreads();

  #pragma unroll 1
  for (int t = 0; t < SEQ; t++) {
    f32x4 aR[4], aZ[4], aNI[4], aNH[4];
    #pragma unroll
    for (int rt = 0; rt < 4; rt++) { aR[rt] = vbr; aZ[rt] = vbz; aNI[rt] = vbni; aNH[rt] = vbnh; }

    uint4 ya[2][4][2];
    #pragma unroll
    for (int ks = 0; ks < 2; ks++)
      #pragma unroll
      for (int rt = 0; rt < 4; rt++) {
        const unsigned int* yp = &ys0[((size_t)t * NBATCH + s0 + rt * 16 + lr) * 64 + ks * 32 + lg * 8];
        ya[ks][rt][0] = *(const uint4*)yp;
        ya[ks][rt][1] = *(const uint4*)(yp + 4);
      }
    #pragma unroll
    for (int ks = 0; ks < 2; ks++) {
      bf16x8 bRh = *(const bf16x8*)&wlds[((w    ) * 2 + ks) * 1024 + l * 8];
      bf16x8 bRl = *(const bf16x8*)&wlds[((w    ) * 2 + ks) * 1024 + 512 + l * 8];
      bf16x8 bZh = *(const bf16x8*)&wlds[((w + 4) * 2 + ks) * 1024 + l * 8];
      bf16x8 bZl = *(const bf16x8*)&wlds[((w + 4) * 2 + ks) * 1024 + 512 + l * 8];
      bf16x8 bNh = *(const bf16x8*)&wlds[((w + 8) * 2 + ks) * 1024 + l * 8];
      bf16x8 bNl = *(const bf16x8*)&wlds[((w + 8) * 2 + ks) * 1024 + 512 + l * 8];
      #pragma unroll
      for (int rt = 0; rt < 4; rt++) {
        bf16x8 Ah, Al;
        {
          B8u H, L;
          unsigned int pp[8] = {ya[ks][rt][0].x, ya[ks][rt][0].y, ya[ks][rt][0].z, ya[ks][rt][0].w,
                                ya[ks][rt][1].x, ya[ks][rt][1].y, ya[ks][rt][1].z, ya[ks][rt][1].w};
          #pragma unroll
          for (int i = 0; i < 8; i++) {
            H.s[i] = (unsigned short)(pp[i] >> 16);
            L.s[i] = (unsigned short)(pp[i] & 0xFFFFu);
          }
          Ah = H.v; Al = L.v;
        }
        aR[rt]  = MFMA_B16(Ah, bRh, aR[rt]);  aR[rt]  = MFMA_B16(Al, bRh, aR[rt]);  aR[rt]  = MFMA_B16(Ah, bRl, aR[rt]);
        aZ[rt]  = MFMA_B16(Ah, bZh, aZ[rt]);  aZ[rt]  = MFMA_B16(Al, bZh, aZ[rt]);  aZ[rt]  = MFMA_B16(Ah, bZl, aZ[rt]);
        aNI[rt] = MFMA_B16(Ah, bNh, aNI[rt]); aNI[rt] = MFMA_B16(Al, bNh, aNI[rt]); aNI[rt] = MFMA_B16(Ah, bNl, aNI[rt]);
      }
    }
    #pragma unroll
    for (int ks = 0; ks < 2; ks++) {
      bf16x8 bRh = *(const bf16x8*)&wlds[24576 + ((w    ) * 2 + ks) * 1024 + l * 8];
      bf16x8 bRl = *(const bf16x8*)&wlds[24576 + ((w    ) * 2 + ks) * 1024 + 512 + l * 8];
      bf16x8 bZh = *(const bf16x8*)&wlds[24576 + ((w + 4) * 2 + ks) * 1024 + l * 8];
      bf16x8 bZl = *(const bf16x8*)&wlds[24576 + ((w + 4) * 2 + ks) * 1024 + 512 + l * 8];
      bf16x8 bNh = *(const bf16x8*)&wlds[24576 + ((w + 8) * 2 + ks) * 1024 + l * 8];
      bf16x8 bNl = *(const bf16x8*)&wlds[24576 + ((w + 8) * 2 + ks) * 1024 + 512 + l * 8];
      #pragma unroll
      for (int rt = 0; rt < 4; rt++) {
        const uint4 p0 = *(const uint4*)&hlds[(rt * 16 + lr) * 68 + ks * 32 + lg * 8];
        const uint4 p1 = *(const uint4*)&hlds[(rt * 16 + lr) * 68 + ks * 32 + lg * 8 + 4];
        bf16x8 Ah, Al;
        {
          B8u H, L;
          unsigned int pp[8] = {p0.x, p0.y, p0.z, p0.w, p1.x, p1.y, p1.z, p1.w};
          #pragma unroll
          for (int i = 0; i < 8; i++) {
            H.s[i] = (unsigned short)(pp[i] >> 16);
            L.s[i] = (unsigned short)(pp[i] & 0xFFFFu);
          }
          Ah = H.v; Al = L.v;
        }
        aR[rt]  = MFMA_B16(Ah, bRh, aR[rt]);  aR[rt]  = MFMA_B16(Al, bRh, aR[rt]);  aR[rt]  = MFMA_B16(Ah, bRl, aR[rt]);
        aZ[rt]  = MFMA_B16(Ah, bZh, aZ[rt]);  aZ[rt]  = MFMA_B16(Al, bZh, aZ[rt]);  aZ[rt]  = MFMA_B16(Ah, bZl, aZ[rt]);
        aNH[rt] = MFMA_B16(Ah, bNh, aNH[rt]); aNH[rt] = MFMA_B16(Al, bNh, aNH[rt]); aNH[rt] = MFMA_B16(Ah, bNl, aNH[rt]);
      }
    }
    __syncthreads();
    #pragma unroll
    for (int rt = 0; rt < 4; rt++) {
      #pragma unroll
      for (int e = 0; e < 4; e++) {
        float rg = sigf(aR[rt][e]);
        float zg = sigf(aZ[rt][e]);
        float n  = tanh_fast(fmaf(rg, aNH[rt][e], aNI[rt][e]));
        float hn = fmaf(zg, hD[rt][e] - n, n);
        hD[rt][e] = hn;
        unsigned int uu = __float_as_uint(hn);
        unsigned int hi = uu & 0xFFFF0000u;
        unsigned int pk = hi | (__float_as_uint(hn - __uint_as_float(hi)) >> 16);
        int sl = rt * 16 + lg * 4 + e;
        hlds[sl * 68 + j] = pk;
        if (t == SEQ - 1) z1[(size_t)(s0 + sl) * 64 + j] = hn;
      }
    }
    __syncthreads();
  }
}

// ===========================================================================
// FALLBACK (small ws): round-2 LDS-weight GRU (verified 455us)
// ===========================================================================
__global__ void prep_kernel(const float* __restrict__ w_ih0, const float* __restrict__ w_hh0,
                            const float* __restrict__ w_ih1, const float* __restrict__ w_hh1,
                            float* __restrict__ wp)
{
  for (int i = blockIdx.x * blockDim.x + threadIdx.x; i < WP_TOTAL; i += gridDim.x * blockDim.x) {
    const float* src;
    int K, rel;
    if (i < WP_HH0)      { src = w_ih0; K = 32; rel = i; }
    else if (i < WP_IH1) { src = w_hh0; K = 64; rel = i - WP_HH0; }
    else if (i < WP_HH1) { src = w_ih1; K = 64; rel = i - WP_IH1; }
    else                 { src = w_hh1; K = 64; rel = i - WP_HH1; }
    int kr = rel & 3;
    int jj = (rel >> 2) & 63;
    int rest = rel >> 8;
    int g = rest % 3;
    int k4 = rest / 3;
    wp[i] = src[(g * 64 + jj) * K + k4 * 4 + kr];
  }
}

__global__ __launch_bounds__(256, 1) void gru_fallback(
    const float* __restrict__ x, const float* __restrict__ wpack,
    const float* __restrict__ b_ih0, const float* __restrict__ b_hh0,
    const float* __restrict__ b_ih1, const float* __restrict__ b_hh1,
    float* __restrict__ zout)
{
  __shared__ float wlds[36864];
  __shared__ float h0s[16][64];
  __shared__ float h1s[16][64];
  const int tid = threadIdx.x;
  {
    const float4* src = (const float4*)(wpack + WP_HH0);
    float4* dst = (float4*)wlds;
    #pragma unroll 4
    for (int i = tid; i < 9216; i += 256) dst[i] = src[i];
  }
  const int j  = tid & 63;
  const int sg = __builtin_amdgcn_readfirstlane(tid >> 6);
  const float br0  = b_ih0[j]      + b_hh0[j];
  const float bz0  = b_ih0[64 + j] + b_hh0[64 + j];
  const float bni0 = b_ih0[128 + j];
  const float bnh0 = b_hh0[128 + j];
  const float br1  = b_ih1[j]      + b_hh1[j];
  const float bz1  = b_ih1[64 + j] + b_hh1[64 + j];
  const float bni1 = b_ih1[128 + j];
  const float bnh1 = b_hh1[128 + j];
  const int s0 = blockIdx.x * 16;
  float h0r[4] = {0.f, 0.f, 0.f, 0.f};
  float h1r[4] = {0.f, 0.f, 0.f, 0.f};
  #pragma unroll
  for (int ss = 0; ss < 4; ss++) { h0s[sg * 4 + ss][j] = 0.f; h1s[sg * 4 + ss][j] = 0.f; }
  __syncthreads();
  const float4* wih0g = (const float4*)(wpack + WP_IH0);
  const float4* whh0l = (const float4*)(wlds);
  const float4* wih1l = (const float4*)(wlds + 12288);
  const float4* whh1l = (const float4*)(wlds + 24576);
  for (int t = 0; t < SEQ; t++) {
    float ar[4], az[4], ani[4], anh[4];
    #pragma unroll
    for (int ss = 0; ss < 4; ss++) { ar[ss] = br0; az[ss] = bz0; ani[ss] = bni0; anh[ss] = bnh0; }
    const float4* xr0 = (const float4*)(x + ((size_t)t * NBATCH + (s0 + sg * 4 + 0)) * FEAT);
    const float4* xr1 = (const float4*)(x + ((size_t)t * NBATCH + (s0 + sg * 4 + 1)) * FEAT);
    const float4* xr2 = (const float4*)(x + ((size_t)t * NBATCH + (s0 + sg * 4 + 2)) * FEAT);
    const float4* xr3 = (const float4*)(x + ((size_t)t * NBATCH + (s0 + sg * 4 + 3)) * FEAT);
    #pragma unroll
    for (int k4 = 0; k4 < 8; k4++) {
      float4 wr = wih0g[(k4 * 3 + 0) * 64 + j];
      float4 wz = wih0g[(k4 * 3 + 1) * 64 + j];
      float4 wn = wih0g[(k4 * 3 + 2) * 64 + j];
      float4 xv[4] = {xr0[k4], xr1[k4], xr2[k4], xr3[k4]};
      #pragma unroll
      for (int ss = 0; ss < 4; ss++) {
        DOT4(ar[ss],  wr, xv[ss]);
        DOT4(az[ss],  wz, xv[ss]);
        DOT4(ani[ss], wn, xv[ss]);
      }
    }
    #pragma unroll
    for (int k4 = 0; k4 < 16; k4++) {
      float4 wr = whh0l[(k4 * 3 + 0) * 64 + j];
      float4 wz = whh0l[(k4 * 3 + 1) * 64 + j];
      float4 wn = whh0l[(k4 * 3 + 2) * 64 + j];
      #pragma unroll
      for (int ss = 0; ss < 4; ss++) {
        float4 hv = *(const float4*)&h0s[sg * 4 + ss][k4 * 4];
        DOT4(ar[ss],  wr, hv);
        DOT4(az[ss],  wz, hv);
        DOT4(anh[ss], wn, hv);
      }
    }
    float h0n[4];
    #pragma unroll
    for (int ss = 0; ss < 4; ss++) {
      float rg = sigf(ar[ss]);
      float zg = sigf(az[ss]);
      float ng = tanh_fast(fmaf(rg, anh[ss], ani[ss]));
      h0n[ss] = fmaf(zg, h0r[ss] - ng, ng);
    }
    __syncthreads();
    #pragma unroll
    for (int ss = 0; ss < 4; ss++) { h0s[sg * 4 + ss][j] = h0n[ss]; h0r[ss] = h0n[ss]; }
    __syncthreads();
    #pragma unroll
    for (int ss = 0; ss < 4; ss++) { ar[ss] = br1; az[ss] = bz1; ani[ss] = bni1; anh[ss] = bnh1; }
    #pragma unroll
    for (int k4 = 0; k4 < 16; k4++) {
      float4 wr = wih1l[(k4 * 3 + 0) * 64 + j];
      float4 wz = wih1l[(k4 * 3 + 1) * 64 + j];
      float4 wn = wih1l[(k4 * 3 + 2) * 64 + j];
      #pragma unroll
      for (int ss = 0; ss < 4; ss++) {
        float4 hv = *(const float4*)&h0s[sg * 4 + ss][k4 * 4];
        DOT4(ar[ss],  wr, hv);
        DOT4(az[ss],  wz, hv);
        DOT4(ani[ss], wn, hv);
      }
    }
    #pragma unroll
    for (int k4 = 0; k4 < 16; k4++) {
      float4 wr = whh1l[(k4 * 3 + 0) * 64 + j];
      float4 wz = whh1l[(k4 * 3 + 1) * 64 + j];
      float4 wn = whh1l[(k4 * 3 + 2) * 64 + j];
      #pragma unroll
      for (int ss = 0; ss < 4; ss++) {
        float4 hv = *(const float4*)&h1s[sg * 4 + ss][k4 * 4];
        DOT4(ar[ss],  wr, hv);
        DOT4(az[ss],  wz, hv);
        DOT4(anh[ss], wn, hv);
      }
    }
    float h1n[4];
    #pragma unroll
    for (int ss = 0; ss < 4; ss++) {
      float rg = sigf(ar[ss]);
      float zg = sigf(az[ss]);
      float ng = tanh_fast(fmaf(rg, anh[ss], ani[ss]));
      h1n[ss] = fmaf(zg, h1r[ss] - ng, ng);
    }
    __syncthreads();
    #pragma unroll
    for (int ss = 0; ss < 4; ss++) { h1s[sg * 4 + ss][j] = h1n[ss]; h1r[ss] = h1n[ss]; }
    __syncthreads();
  }
  #pragma unroll
  for (int ss = 0; ss < 4; ss++) {
    int s = s0 + sg * 4 + ss;
    zout[(size_t)s * 64 + j]            = h0r[ss];
    zout[(size_t)(NBATCH + s) * 64 + j] = h1r[ss];
  }
}

// ===========================================================================
// MFMA GAT: flash attention per (lb, 64-row tile), split-bf16 3-term MFMA.
// LDS tiles stride 68 u32/f32 -> all frag reads/writes <=2-way banked.
//   KT[s][d]  packed hi|lo  : B-frags for QK^T
//   VT[d][s]  packed hi|lo  : B-frags for P.V
//   PS[row][s] f32          : P, written/read by same wave (no barrier)
// ===========================================================================
__global__ __launch_bounds__(256, 2) void gat_mfma(const float* __restrict__ z,
                                                   const int* __restrict__ mask,
                                                   float* __restrict__ out)
{
  __shared__ unsigned int KT[64 * 68];
  __shared__ unsigned int VT[64 * 68];
  __shared__ float        PS[64 * 68];
  const int tid = threadIdx.x;
  const int w = tid >> 6, l = tid & 63, lr = l & 15, lg = l >> 4;
  const int rt = blockIdx.x & 15;
  const int lb = blockIdx.x >> 4;
  const float* zb = z + (size_t)lb * 1024 * 64;
  const int n0 = rt * 64;

  // Q split A-frags in registers: rows n0 + w*16 + (l&15), k = ks*32 + lg*8 + e
  bf16x8 Qh[2], Ql[2];
  #pragma unroll
  for (int ks = 0; ks < 2; ks++) {
    const float* qp = zb + (size_t)(n0 + w * 16 + lr) * 64 + ks * 32 + lg * 8;
    float4 a0 = *(const float4*)qp;
    float4 a1 = *(const float4*)(qp + 4);
    float fa[8] = {a0.x, a0.y, a0.z, a0.w, a1.x, a1.y, a1.z, a1.w};
    B8u H, L;
    #pragma unroll
    for (int i = 0; i < 8; i++) {
      unsigned int u = __float_as_uint(fa[i]);
      unsigned int hi = u & 0xFFFF0000u;
      H.s[i] = (unsigned short)(hi >> 16);
      L.s[i] = (unsigned short)(__float_as_uint(fa[i] - __uint_as_float(hi)) >> 16);
    }
    Qh[ks] = H.v; Ql[ks] = L.v;
  }

  f32x4 O[4];
  float M[4], D[4];
  #pragma unroll
  for (int ct = 0; ct < 4; ct++)
    #pragma unroll
    for (int e = 0; e < 4; e++) O[ct][e] = 0.f;
  #pragma unroll
  for (int e = 0; e < 4; e++) { M[e] = -INFINITY; D[e] = 0.f; }

  for (int mt = 0; mt < 16; mt++) {
    __syncthreads();   // previous tile's frag reads complete
    // stage KT natural [s][d]
    #pragma unroll
    for (int k = 0; k < 4; k++) {
      int idx = tid + k * 256;
      int row = idx >> 4, q = idx & 15;
      float4 a = *(const float4*)(zb + (size_t)(mt * 64 + row) * 64 + q * 4);
      uint4 pk = make_uint4(packsplit(a.x), packsplit(a.y), packsplit(a.z), packsplit(a.w));
      *(uint4*)&KT[row * 68 + q * 4] = pk;
    }
    // stage VT transposed [d][s]
    {
      int d = tid & 63, g = tid >> 6;
      unsigned int tmp[16];
      #pragma unroll
      for (int r = 0; r < 16; r++)
        tmp[r] = packsplit(zb[(size_t)(mt * 64 + g * 16 + r) * 64 + d]);
      #pragma unroll
      for (int q = 0; q < 4; q++)
        *(uint4*)&VT[d * 68 + g * 16 + q * 4] =
            make_uint4(tmp[q * 4], tmp[q * 4 + 1], tmp[q * 4 + 2], tmp[q * 4 + 3]);
    }
    __syncthreads();

    // ---- S = Q . K^T (split 3-term) ----
    f32x4 S[4];
    #pragma unroll
    for (int ct = 0; ct < 4; ct++)
      #pragma unroll
      for (int e = 0; e < 4; e++) S[ct][e] = 0.f;
    #pragma unroll
    for (int ks = 0; ks < 2; ks++) {
      #pragma unroll
      for (int ct = 0; ct < 4; ct++) {
        bf16x8 Kh, Kl;
        unpack8(&KT[(ct * 16 + lr) * 68 + ks * 32 + lg * 8], Kh, Kl);
        S[ct] = MFMA_B16(Qh[ks], Kh, S[ct]);
        S[ct] = MFMA_B16(Ql[ks], Kh, S[ct]);
        S[ct] = MFMA_B16(Qh[ks], Kl, S[ct]);
      }
    }

    // ---- leaky_relu * mask, masked_fill(==0,-1e16)  (D-layout: row lg*4+e, col ct*16+lr) ----
    #pragma unroll
    for (int ct = 0; ct < 4; ct++) {
      #pragma unroll
      for (int e = 0; e < 4; e++) {
        int mm = mask[(size_t)(n0 + w * 16 + lg * 4 + e) * 1024 + mt * 64 + ct * 16 + lr];
        float v = S[ct][e];
        float lrv = v > 0.f ? v : 0.1f * v;
        float a = mm ? lrv : 0.f;
        S[ct][e] = (a == 0.f) ? -1e16f : a;
      }
    }

    // ---- online softmax over the 64 cols (4 ct in-thread, 16 lanes via shfl) ----
    #pragma unroll
    for (int e = 0; e < 4; e++) {
      float m = fmaxf(fmaxf(S[0][e], S[1][e]), fmaxf(S[2][e], S[3][e]));
      #pragma unroll
      for (int sw = 1; sw < 16; sw <<= 1) m = fmaxf(m, __shfl_xor(m, sw, 16));
      float newM = fmaxf(M[e], m);
      float sc = __expf(M[e] - newM);
      float ps = 0.f;
      float pv[4];
      #pragma unroll
      for (int ct = 0; ct < 4; ct++) {
        pv[ct] = __expf(S[ct][e] - newM);
        ps += pv[ct];
      }
      #pragma unroll
      for (int sw = 1; sw < 16; sw <<= 1) ps += __shfl_xor(ps, sw, 16);
      D[e] = D[e] * sc + ps;
      M[e] = newM;
      #pragma unroll
      for (int ct = 0; ct < 4; ct++) {
        O[ct][e] *= sc;
        PS[(w * 16 + lg * 4 + e) * 68 + ct * 16 + lr] = pv[ct];
      }
    }

    // ---- O += P . V  (A = P from LDS, same wave; B = VT frags) ----
    #pragma unroll
    for (int ks = 0; ks < 2; ks++) {
      const float* pp = &PS[(w * 16 + lr) * 68 + ks * 32 + lg * 8];
      float4 p0 = *(const float4*)pp;
      float4 p1 = *(const float4*)(pp + 4);
      float fa[8] = {p0.x, p0.y, p0.z, p0.w, p1.x, p1.y, p1.z, p1.w};
      bf16x8 Ph, Pl;
      {
        B8u H, L;
        #pragma unroll
        for (int i = 0; i < 8; i++) {
          unsigned int u = __float_as_uint(fa[i]);
          unsigned int hi = u & 0xFFFF0000u;
          H.s[i] = (unsigned short)(hi >> 16);
          L.s[i] = (unsigned short)(__float_as_uint(fa[i] - __uint_as_float(hi)) >> 16);
        }
        Ph = H.v; Pl = L.v;
      }
      #pragma unroll
      for (int ct = 0; ct < 4; ct++) {
        bf16x8 Vh, Vl;
        unpack8(&VT[(ct * 16 + lr) * 68 + ks * 32 + lg * 8], Vh, Vl);
        O[ct] = MFMA_B16(Ph, Vh, O[ct]);
        O[ct] = MFMA_B16(Pl, Vh, O[ct]);
        O[ct] = MFMA_B16(Ph, Vl, O[ct]);
      }
    }
  }

  // ---- epilogue: divide by denom, store ----
  #pragma unroll
  for (int e = 0; e < 4; e++) {
    float inv = 1.0f / D[e];
    size_t rowo = ((size_t)lb * 1024 + n0 + w * 16 + lg * 4 + e) * 64;
    #pragma unroll
    for (int ct = 0; ct < 4; ct++)
      out[rowo + ct * 16 + lr] = O[ct][e] * inv;
  }
}

extern "C" void kernel_launch(void* const* d_in, const int* in_sizes, int n_in,
                              void* d_out, int out_size, void* d_ws, size_t ws_size,
                              hipStream_t stream) {
  const float* h     = (const float*)d_in[0];
  const int*   mask  = (const int*)d_in[1];
  const float* w_ih0 = (const float*)d_in[2];
  const float* w_hh0 = (const float*)d_in[3];
  const float* b_ih0 = (const float*)d_in[4];
  const float* b_hh0 = (const float*)d_in[5];
  const float* w_ih1 = (const float*)d_in[6];
  const float* w_hh1 = (const float*)d_in[7];
  const float* b_ih1 = (const float*)d_in[8];
  const float* b_hh1 = (const float*)d_in[9];
  float* out = (float*)d_out;

  char* wsb = (char*)d_ws;
  float* zws = (float*)wsb;                                   // [2][16384][64] fp32
  const size_t Z_BYTES  = (size_t)2 * NBATCH * 64 * 4;        // 8388608
  const size_t YS_OFF   = Z_BYTES + 176128;                   // past 172KB frag weights
  const size_t NEED_FAST = YS_OFF + (size_t)SEQ * NBATCH * 64 * 4;

  if (ws_size >= NEED_FAST) {
    unsigned short* wfrag = (unsigned short*)(wsb + Z_BYTES);
    unsigned int*   ys0   = (unsigned int*)(wsb + YS_OFF);
    prep_frag_kernel<<<168, 256, 0, stream>>>(w_ih0, w_hh0, w_ih1, w_hh1, wfrag);
    gru_l0<<<256, 256, 0, stream>>>(h, wfrag, b_ih0, b_hh0, zws, ys0);
    gru_l1<<<256, 256, 0, stream>>>(ys0, wfrag, b_ih1, b_hh1, zws + (size_t)NBATCH * 64);
  } else {
    float* wpack = (float*)(wsb + Z_BYTES);
    prep_kernel<<<24, 256, 0, stream>>>(w_ih0, w_hh0, w_ih1, w_hh1, wpack);
    gru_fallback<<<1024, 256, 0, stream>>>(h, wpack, b_ih0, b_hh0, b_ih1, b_hh1, zws);
  }
  gat_mfma<<<512, 256, 0, stream>>>(zws, mask, out);
}